// Round 7
// baseline (70.289 us; speedup 1.0000x reference)
//
#include <hip/hip_runtime.h>

#define NSUB   10000
#define NCLS   17
#define NG     500
#define NE     80000
#define HIDN   8
#define NEG_SLOPE 0.2f

typedef __attribute__((ext_vector_type(8))) short short8;
typedef __attribute__((ext_vector_type(4))) float f32x4;

// ws layout (float units)
#define OFF_B1   0                        // 512x64 bf16 = 16384 float slots
#define OFF_B2   16384                    // 512x32 bf16 = 8192 float slots
#define OFF_D    (OFF_B2 + 8192)          // 32
#define OFF_XL   (OFF_D + 32)             // NSUB*8
#define OFF_XR   (OFF_XL + NSUB*HIDN)     // NSUB*8
#define OFF_PP   (OFF_XR + NSUB*HIDN)     // NSUB*20 (P padded, pad=0)
#define OFF_LL   (OFF_PP + NSUB*20)       // NSUB*20 (logP padded, pad=0)
#define OFF_NUM  (OFF_LL + NSUB*20)       // NSUB
#define OFF_DEN  (OFF_NUM + NSUB)         // NSUB
#define OFF_DONE (OFF_DEN + NSUB)         // 1 uint (edge-block done counter)

__device__ __forceinline__ unsigned short f2bf(float f) {
    unsigned u = __float_as_uint(f);
    u += 0x7FFFu + ((u >> 16) & 1u);      // round-to-nearest-even
    return (unsigned short)(u >> 16);
}

#define MFMA16 __builtin_amdgcn_mfma_f32_16x16x32_bf16

// ---- prep: B1/B2 bf16 fragments, D[c], zero out[0..1] + NUM/DEN/done ----
__global__ void k_prep(const float* __restrict__ Mu, const float* __restrict__ Var,
                       const float* __restrict__ Wl, const float* __restrict__ Wr,
                       unsigned short* __restrict__ B1, unsigned short* __restrict__ B2,
                       float* __restrict__ D, float* __restrict__ zeroBase,
                       float* __restrict__ out) {
    const int b = blockIdx.x;
    if (b < 4) {
        const int t = b * 256 + threadIdx.x;        // 1024 threads = 16 ksteps * 64 lanes
        const int ks = t >> 6, lane = t & 63;
        const int fgrp = lane >> 4, fj = lane & 15;
        unsigned short v1[4][8], v2[2][8];
        #pragma unroll
        for (int e = 0; e < 8; e++) {
            const int g = ks * 32 + fgrp * 8 + e;
            const bool gv = (g < NG);
            #pragma unroll
            for (int nt = 0; nt < 4; nt++) {
                const int col = nt * 16 + fj;
                float v = 0.f;
                if (gv) {
                    if (col >= 17 && col < 34)      v = Mu[(col - 17) * NG + g] / Var[(col - 17) * NG + g];
                    else if (col >= 34 && col < 42) v = Wl[g * HIDN + (col - 34)];
                    else if (col >= 42 && col < 50) v = Wr[g * HIDN + (col - 42)];
                }
                v1[nt][e] = f2bf(v);
            }
            #pragma unroll
            for (int nt = 0; nt < 2; nt++) {
                const int col = nt * 16 + fj;
                float v = 0.f;
                if (gv && col < NCLS) v = 1.0f / Var[col * NG + g];
                v2[nt][e] = f2bf(v);
            }
        }
        #pragma unroll
        for (int nt = 0; nt < 4; nt++)
            *reinterpret_cast<short8*>(B1 + (size_t)((ks * 4 + nt) * 64 + lane) * 8) =
                *reinterpret_cast<short8*>(v1[nt]);
        #pragma unroll
        for (int nt = 0; nt < 2; nt++)
            *reinterpret_cast<short8*>(B2 + (size_t)((ks * 2 + nt) * 64 + lane) * 8) =
                *reinterpret_cast<short8*>(v2[nt]);
    } else if (b < 21) {
        const int c = b - 4;
        float s = 0.f;
        for (int g = threadIdx.x; g < NG; g += 256) {
            const float m = Mu[c * NG + g];
            s += m * m / Var[c * NG + g];
        }
        __shared__ float red[4];
        #pragma unroll
        for (int o = 32; o; o >>= 1) s += __shfl_xor(s, o);
        const int w = threadIdx.x >> 6, l = threadIdx.x & 63;
        if (l == 0) red[w] = s;
        __syncthreads();
        if (threadIdx.x == 0) D[c] = red[0] + red[1] + red[2] + red[3];
    } else {
        const int i = (b - 21) * 256 + threadIdx.x;   // zero NUM/DEN/done (2*NSUB+1)
        if (i < 2 * NSUB + 1) zeroBase[i] = 0.f;
        if (b == 21 && threadIdx.x < 2) out[threadIdx.x] = 0.f;
    }
}

// ---- per-cell: MFMA GEMM, 1 tile (16 cells) per block, K split across 4 waves ----
// Prologue issues ALL x-loads up front (single HBM-latency exposure per wave),
// then converts, then 4 unrolled KSTEPs whose 24 B-loads the compiler can hoist.
__launch_bounds__(256, 2)
__global__ void k_cell(const float* __restrict__ x, const int* __restrict__ sidx,
                       const float* __restrict__ Wp, const float* __restrict__ Sp,
                       const float* __restrict__ blv, const float* __restrict__ brv,
                       const unsigned short* __restrict__ B1,
                       const unsigned short* __restrict__ B2,
                       const float* __restrict__ D,
                       float* __restrict__ out, float* __restrict__ XL,
                       float* __restrict__ XR, float* __restrict__ PP,
                       float* __restrict__ LL) {
    const int tid = threadIdx.x;
    const int w = tid >> 6, l = tid & 63;
    const int grp = l >> 4, j = l & 15;
    const int rowbase = blockIdx.x * 16;             // 625 tiles exactly
    const int ks0 = w * 4;

    const float* xr = x + (size_t)(rowbase + j) * NG;

    // ---- prologue: issue all 8 x float4 loads ----
    float4 xv0, xv1, xv2, xv3, xv4, xv5, xv6, xv7;
    {
        const int ga = ks0 * 32 + grp * 8;
        xv0 = *reinterpret_cast<const float4*>(xr + ga);
        xv1 = *reinterpret_cast<const float4*>(xr + ga + 4);
        xv2 = *reinterpret_cast<const float4*>(xr + ga + 32);
        xv3 = *reinterpret_cast<const float4*>(xr + ga + 36);
        xv4 = *reinterpret_cast<const float4*>(xr + ga + 64);
        xv5 = *reinterpret_cast<const float4*>(xr + ga + 68);
        if (w < 3) {
            xv6 = *reinterpret_cast<const float4*>(xr + ga + 96);
            xv7 = *reinterpret_cast<const float4*>(xr + ga + 100);
        } else {                                     // ks=15 tail: genes 480..499 valid
            const int g0 = 480 + grp * 8;            // == ga + 96 for w==3
            xv6 = float4{0.f, 0.f, 0.f, 0.f};
            xv7 = float4{0.f, 0.f, 0.f, 0.f};
            if (g0 <= 496) xv6 = *reinterpret_cast<const float4*>(xr + g0);
            if (g0 <= 488) xv7 = *reinterpret_cast<const float4*>(xr + g0 + 4);
        }
    }

    // ---- convert all fragments (x raw regs die here) ----
    short8 fa0, fb0, fa1, fb1, fa2v, fb2, fa3, fb3;
#define CVT(v0, v1, fa, fb)                                                   \
    {                                                                         \
        const float xs[8] = { v0.x, v0.y, v0.z, v0.w, v1.x, v1.y, v1.z, v1.w };\
        _Pragma("unroll")                                                     \
        for (int e = 0; e < 8; e++) {                                         \
            fa[e] = (short)f2bf(xs[e]);                                       \
            fb[e] = (short)f2bf(xs[e] * xs[e]);                               \
        }                                                                     \
    }
    CVT(xv0, xv1, fa0, fb0)
    CVT(xv2, xv3, fa1, fb1)
    CVT(xv4, xv5, fa2v, fb2)
    CVT(xv6, xv7, fa3, fb3)
#undef CVT

    f32x4 a0 = {0,0,0,0}, a1 = {0,0,0,0}, a2 = {0,0,0,0}, a3 = {0,0,0,0};
    const short8* b1 = reinterpret_cast<const short8*>(B1);
    const short8* b2 = reinterpret_cast<const short8*>(B2);

#define KSTEP(ks, fa, fb)                                                \
    {                                                                    \
        const short8* p1 = b1 + (size_t)((ks) * 4) * 64 + l;             \
        const short8* p2 = b2 + (size_t)((ks) * 2) * 64 + l;             \
        a0 = MFMA16(fa, p1[0],   a0, 0, 0, 0);                           \
        a1 = MFMA16(fa, p1[64],  a1, 0, 0, 0);                           \
        a2 = MFMA16(fa, p1[128], a2, 0, 0, 0);                           \
        a3 = MFMA16(fa, p1[192], a3, 0, 0, 0);                           \
        a0 = MFMA16(fb, p2[0],   a0, 0, 0, 0);                           \
        a1 = MFMA16(fb, p2[64],  a1, 0, 0, 0);                           \
    }
    KSTEP(ks0 + 0, fa0, fb0)
    KSTEP(ks0 + 1, fa1, fb1)
    KSTEP(ks0 + 2, fa2v, fb2)
    KSTEP(ks0 + 3, fa3, fb3)
#undef KSTEP

    // C layout: row = grp*4 + r, col = nt*16 + j (m89-verified)
    __shared__ float ct[4][16][68];
    #pragma unroll
    for (int r = 0; r < 4; r++) {
        ct[w][grp * 4 + r][j]      = a0[r];
        ct[w][grp * 4 + r][16 + j] = a1[r];
        ct[w][grp * 4 + r][32 + j] = a2[r];
        ct[w][grp * 4 + r][48 + j] = a3[r];
    }
    __syncthreads();

    if (w == 0) {
        float ll = 0.f;
        if (l < 16) {
            const int cell = rowbase + l;
            const int idx = sidx[cell];
            const float* wrow = Wp + (size_t)idx * NCLS;
            float p[NCLS];
            float mx = -1e30f;
            #pragma unroll
            for (int c = 0; c < NCLS; c++) { p[c] = wrow[c]; mx = fmaxf(mx, p[c]); }
            float sum = 0.f;
            #pragma unroll
            for (int c = 0; c < NCLS; c++) { p[c] = __expf(p[c] - mx); sum += p[c]; }
            const float inv = 1.0f / sum;
            const float s = Sp[idx];
            float* orow = out + 2 + (size_t)cell * NCLS;
            float* prow = PP + (size_t)cell * 20;
            float* lrow = LL + (size_t)cell * 20;
            #pragma unroll
            for (int c = 0; c < NCLS; c++) {
                p[c] *= inv;
                const float lg = __logf(p[c] + 1e-8f);
                orow[c] = p[c];
                prow[c] = p[c];
                lrow[c] = lg;
                const float T1 = ct[0][l][c] + ct[1][l][c] + ct[2][l][c] + ct[3][l][c];
                const float T2 = ct[0][l][NCLS + c] + ct[1][l][NCLS + c]
                               + ct[2][l][NCLS + c] + ct[3][l][NCLS + c];
                ll += p[c] * (-0.5f * T1 + s * T2 - 0.5f * s * s * D[c]);
            }
            prow[17] = 0.f; prow[18] = 0.f; prow[19] = 0.f;
            lrow[17] = 0.f; lrow[18] = 0.f; lrow[19] = 0.f;
            #pragma unroll
            for (int h = 0; h < HIDN; h++) {
                XL[cell * HIDN + h] = ct[0][l][34 + h] + ct[1][l][34 + h]
                                    + ct[2][l][34 + h] + ct[3][l][34 + h] + blv[h];
                XR[cell * HIDN + h] = ct[0][l][42 + h] + ct[1][l][42 + h]
                                    + ct[2][l][42 + h] + ct[3][l][42 + h] + brv[h];
            }
        }
        #pragma unroll
        for (int o = 32; o; o >>= 1) ll += __shfl_xor(ll, o);
        if (l == 0) atomicAdd(out, ll * (1.0f / NSUB));
    }
}

// ---- fused edge + (last block) node reduce ----
__global__ void k_edge(const int* __restrict__ ei, const float* __restrict__ XL,
                       const float* __restrict__ XR, const float* __restrict__ att,
                       const float* __restrict__ PP, const float* __restrict__ LL,
                       float* __restrict__ NUM, float* __restrict__ DEN,
                       unsigned* __restrict__ done, float* __restrict__ out) {
    const int tid = threadIdx.x;
    const int k = blockIdx.x * 256 + tid;
    if (k < NE) {
        const int s = ei[k], d = ei[NE + k];
        const float4 xa0 = *reinterpret_cast<const float4*>(XL + s * HIDN);
        const float4 xa1 = *reinterpret_cast<const float4*>(XL + s * HIDN + 4);
        const float4 xb0 = *reinterpret_cast<const float4*>(XR + d * HIDN);
        const float4 xb1 = *reinterpret_cast<const float4*>(XR + d * HIDN + 4);
        const float hv[8] = { xa0.x + xb0.x, xa0.y + xb0.y, xa0.z + xb0.z, xa0.w + xb0.w,
                              xa1.x + xb1.x, xa1.y + xb1.y, xa1.z + xb1.z, xa1.w + xb1.w };
        float e = 0.f;
        #pragma unroll
        for (int h = 0; h < HIDN; h++) {
            const float v = hv[h];
            e += ((v > 0.f) ? v : NEG_SLOPE * v) * att[h];
        }
        const float ex = __expf(e);        // no max-shift: |e| <~ 8, exp in f32 range
        float wgt = 0.f;
        #pragma unroll
        for (int q = 0; q < 5; q++) {
            const float4 ps = *reinterpret_cast<const float4*>(PP + (size_t)s * 20 + q * 4);
            const float4 ld = *reinterpret_cast<const float4*>(LL + (size_t)d * 20 + q * 4);
            wgt += ps.x * ld.x + ps.y * ld.y + ps.z * ld.z + ps.w * ld.w;
        }
        atomicAdd(NUM + d, ex * wgt);
        atomicAdd(DEN + d, ex);
    }

    // done-counter: last block to finish performs the node reduction
    __shared__ bool lastb;
    __syncthreads();                       // drains each thread's atomics (vmcnt(0))
    if (tid == 0) {
        __threadfence();                   // release: make this block's atomics visible
        lastb = (atomicAdd(done, 1u) == gridDim.x - 1);
    }
    __syncthreads();
    if (lastb) {
        __threadfence();                   // acquire: fresh NUM/DEN reads
        float v = 0.f;
        for (int n = tid; n < NSUB; n += 256) {
            const float dd = DEN[n];
            if (dd > 0.f) v += NUM[n] / dd;
        }
        #pragma unroll
        for (int o = 32; o; o >>= 1) v += __shfl_xor(v, o);
        if ((tid & 63) == 0) atomicAdd(out + 1, -v * (1.0f / NSUB));
    }
}

extern "C" void kernel_launch(void* const* d_in, const int* in_sizes, int n_in,
                              void* d_out, int out_size, void* d_ws, size_t ws_size,
                              hipStream_t stream) {
    const float* x    = (const float*)d_in[0];
    const float* Mu   = (const float*)d_in[1];
    const float* Var  = (const float*)d_in[2];
    const int*   ei   = (const int*)d_in[3];
    const int*   sidx = (const int*)d_in[4];
    const float* Wp   = (const float*)d_in[5];
    const float* Sp   = (const float*)d_in[6];
    const float* Wl   = (const float*)d_in[7];
    const float* bl   = (const float*)d_in[8];
    const float* Wr   = (const float*)d_in[9];
    const float* br   = (const float*)d_in[10];
    const float* att  = (const float*)d_in[11];
    float* out = (float*)d_out;
    float* ws  = (float*)d_ws;

    unsigned short* B1 = (unsigned short*)(ws + OFF_B1);
    unsigned short* B2 = (unsigned short*)(ws + OFF_B2);
    float* D    = ws + OFF_D;
    float* XL   = ws + OFF_XL;
    float* XR   = ws + OFF_XR;
    float* PP   = ws + OFF_PP;
    float* LL   = ws + OFF_LL;
    float* NUM  = ws + OFF_NUM;
    float* DEN  = ws + OFF_DEN;
    unsigned* done = (unsigned*)(ws + OFF_DONE);

    (void)in_sizes; (void)n_in; (void)out_size; (void)ws_size;

    // 4 (frag) + 17 (D) + 79 (zero NUM/DEN/done + out[0..1])
    k_prep<<<100, 256, 0, stream>>>(Mu, Var, Wl, Wr, B1, B2, D, NUM, out);
    k_cell<<<NSUB / 16, 256, 0, stream>>>(x, sidx, Wp, Sp, bl, br, B1, B2, D,
                                          out, XL, XR, PP, LL);
    k_edge<<<(NE + 255) / 256, 256, 0, stream>>>(ei, XL, XR, att, PP, LL, NUM, DEN,
                                                 done, out);
}

// Round 8
// 65.865 us; speedup vs baseline: 1.0672x; 1.0672x over previous
//
#include <hip/hip_runtime.h>

#define NSUB   10000
#define NCLS   17
#define NG     500
#define NE     80000
#define HIDN   8
#define NEG_SLOPE 0.2f

typedef __attribute__((ext_vector_type(8))) short short8;
typedef __attribute__((ext_vector_type(4))) float f32x4;

// ws layout (float units)
#define OFF_B1   0                        // 512x64 bf16 = 16384 float slots
#define OFF_B2   16384                    // 512x32 bf16 = 8192 float slots
#define OFF_D    (OFF_B2 + 8192)          // 32
#define OFF_XL   (OFF_D + 32)             // NSUB*8
#define OFF_XR   (OFF_XL + NSUB*HIDN)     // NSUB*8
#define OFF_PP   (OFF_XR + NSUB*HIDN)     // NSUB*20 (P padded, pad=0)
#define OFF_LL   (OFF_PP + NSUB*20)       // NSUB*20 (logP padded, pad=0)
#define OFF_NUM  (OFF_LL + NSUB*20)       // NSUB
#define OFF_DEN  (OFF_NUM + NSUB)         // NSUB
#define OFF_DONE (OFF_DEN + NSUB)         // 1 uint (edge-block done counter)

__device__ __forceinline__ unsigned short f2bf(float f) {
    unsigned u = __float_as_uint(f);
    u += 0x7FFFu + ((u >> 16) & 1u);      // round-to-nearest-even
    return (unsigned short)(u >> 16);
}

#define MFMA16 __builtin_amdgcn_mfma_f32_16x16x32_bf16

// ---- prep: B1/B2 bf16 fragments, D[c], zero out[0..1] + NUM/DEN/done ----
__global__ void k_prep(const float* __restrict__ Mu, const float* __restrict__ Var,
                       const float* __restrict__ Wl, const float* __restrict__ Wr,
                       unsigned short* __restrict__ B1, unsigned short* __restrict__ B2,
                       float* __restrict__ D, float* __restrict__ zeroBase,
                       float* __restrict__ out) {
    const int b = blockIdx.x;
    if (b < 4) {
        const int t = b * 256 + threadIdx.x;        // 1024 threads = 16 ksteps * 64 lanes
        const int ks = t >> 6, lane = t & 63;
        const int fgrp = lane >> 4, fj = lane & 15;
        unsigned short v1[4][8], v2[2][8];
        #pragma unroll
        for (int e = 0; e < 8; e++) {
            const int g = ks * 32 + fgrp * 8 + e;
            const bool gv = (g < NG);
            #pragma unroll
            for (int nt = 0; nt < 4; nt++) {
                const int col = nt * 16 + fj;
                float v = 0.f;
                if (gv) {
                    if (col >= 17 && col < 34)      v = Mu[(col - 17) * NG + g] / Var[(col - 17) * NG + g];
                    else if (col >= 34 && col < 42) v = Wl[g * HIDN + (col - 34)];
                    else if (col >= 42 && col < 50) v = Wr[g * HIDN + (col - 42)];
                }
                v1[nt][e] = f2bf(v);
            }
            #pragma unroll
            for (int nt = 0; nt < 2; nt++) {
                const int col = nt * 16 + fj;
                float v = 0.f;
                if (gv && col < NCLS) v = 1.0f / Var[col * NG + g];
                v2[nt][e] = f2bf(v);
            }
        }
        #pragma unroll
        for (int nt = 0; nt < 4; nt++)
            *reinterpret_cast<short8*>(B1 + (size_t)((ks * 4 + nt) * 64 + lane) * 8) =
                *reinterpret_cast<short8*>(v1[nt]);
        #pragma unroll
        for (int nt = 0; nt < 2; nt++)
            *reinterpret_cast<short8*>(B2 + (size_t)((ks * 2 + nt) * 64 + lane) * 8) =
                *reinterpret_cast<short8*>(v2[nt]);
    } else if (b < 21) {
        const int c = b - 4;
        float s = 0.f;
        for (int g = threadIdx.x; g < NG; g += 256) {
            const float m = Mu[c * NG + g];
            s += m * m / Var[c * NG + g];
        }
        __shared__ float red[4];
        #pragma unroll
        for (int o = 32; o; o >>= 1) s += __shfl_xor(s, o);
        const int w = threadIdx.x >> 6, l = threadIdx.x & 63;
        if (l == 0) red[w] = s;
        __syncthreads();
        if (threadIdx.x == 0) D[c] = red[0] + red[1] + red[2] + red[3];
    } else {
        const int i = (b - 21) * 256 + threadIdx.x;   // zero NUM/DEN/done (2*NSUB+1)
        if (i < 2 * NSUB + 1) zeroBase[i] = 0.f;
        if (b == 21 && threadIdx.x < 2) out[threadIdx.x] = 0.f;
    }
}

// ---- per-cell: MFMA GEMM, 1 tile (16 cells) per block, K split across 4 waves ----
__launch_bounds__(256, 2)
__global__ void k_cell(const float* __restrict__ x, const int* __restrict__ sidx,
                       const float* __restrict__ Wp, const float* __restrict__ Sp,
                       const float* __restrict__ blv, const float* __restrict__ brv,
                       const unsigned short* __restrict__ B1,
                       const unsigned short* __restrict__ B2,
                       const float* __restrict__ D,
                       float* __restrict__ out, float* __restrict__ XL,
                       float* __restrict__ XR, float* __restrict__ PP,
                       float* __restrict__ LL) {
    const int tid = threadIdx.x;
    const int w = tid >> 6, l = tid & 63;
    const int grp = l >> 4, j = l & 15;
    const int rowbase = blockIdx.x * 16;             // 625 tiles exactly
    const int ks0 = w * 4;

    const float* xr = x + (size_t)(rowbase + j) * NG;

    // ---- prologue: issue all 8 x float4 loads ----
    float4 xv0, xv1, xv2, xv3, xv4, xv5, xv6, xv7;
    {
        const int ga = ks0 * 32 + grp * 8;
        xv0 = *reinterpret_cast<const float4*>(xr + ga);
        xv1 = *reinterpret_cast<const float4*>(xr + ga + 4);
        xv2 = *reinterpret_cast<const float4*>(xr + ga + 32);
        xv3 = *reinterpret_cast<const float4*>(xr + ga + 36);
        xv4 = *reinterpret_cast<const float4*>(xr + ga + 64);
        xv5 = *reinterpret_cast<const float4*>(xr + ga + 68);
        if (w < 3) {
            xv6 = *reinterpret_cast<const float4*>(xr + ga + 96);
            xv7 = *reinterpret_cast<const float4*>(xr + ga + 100);
        } else {                                     // ks=15 tail: genes 480..499 valid
            const int g0 = 480 + grp * 8;
            xv6 = float4{0.f, 0.f, 0.f, 0.f};
            xv7 = float4{0.f, 0.f, 0.f, 0.f};
            if (g0 <= 496) xv6 = *reinterpret_cast<const float4*>(xr + g0);
            if (g0 <= 488) xv7 = *reinterpret_cast<const float4*>(xr + g0 + 4);
        }
    }

    // ---- convert all fragments ----
    short8 fa0, fb0, fa1, fb1, fa2v, fb2, fa3, fb3;
#define CVT(v0, v1, fa, fb)                                                   \
    {                                                                         \
        const float xs[8] = { v0.x, v0.y, v0.z, v0.w, v1.x, v1.y, v1.z, v1.w };\
        _Pragma("unroll")                                                     \
        for (int e = 0; e < 8; e++) {                                         \
            fa[e] = (short)f2bf(xs[e]);                                       \
            fb[e] = (short)f2bf(xs[e] * xs[e]);                               \
        }                                                                     \
    }
    CVT(xv0, xv1, fa0, fb0)
    CVT(xv2, xv3, fa1, fb1)
    CVT(xv4, xv5, fa2v, fb2)
    CVT(xv6, xv7, fa3, fb3)
#undef CVT

    f32x4 a0 = {0,0,0,0}, a1 = {0,0,0,0}, a2 = {0,0,0,0}, a3 = {0,0,0,0};
    const short8* b1 = reinterpret_cast<const short8*>(B1);
    const short8* b2 = reinterpret_cast<const short8*>(B2);

#define KSTEP(ks, fa, fb)                                                \
    {                                                                    \
        const short8* p1 = b1 + (size_t)((ks) * 4) * 64 + l;             \
        const short8* p2 = b2 + (size_t)((ks) * 2) * 64 + l;             \
        a0 = MFMA16(fa, p1[0],   a0, 0, 0, 0);                           \
        a1 = MFMA16(fa, p1[64],  a1, 0, 0, 0);                           \
        a2 = MFMA16(fa, p1[128], a2, 0, 0, 0);                           \
        a3 = MFMA16(fa, p1[192], a3, 0, 0, 0);                           \
        a0 = MFMA16(fb, p2[0],   a0, 0, 0, 0);                           \
        a1 = MFMA16(fb, p2[64],  a1, 0, 0, 0);                           \
    }
    KSTEP(ks0 + 0, fa0, fb0)
    KSTEP(ks0 + 1, fa1, fb1)
    KSTEP(ks0 + 2, fa2v, fb2)
    KSTEP(ks0 + 3, fa3, fb3)
#undef KSTEP

    // C layout: row = grp*4 + r, col = nt*16 + j (m89-verified)
    __shared__ float ct[4][16][68];
    #pragma unroll
    for (int r = 0; r < 4; r++) {
        ct[w][grp * 4 + r][j]      = a0[r];
        ct[w][grp * 4 + r][16 + j] = a1[r];
        ct[w][grp * 4 + r][32 + j] = a2[r];
        ct[w][grp * 4 + r][48 + j] = a3[r];
    }
    __syncthreads();

    if (w == 0) {
        float ll = 0.f;
        if (l < 16) {
            const int cell = rowbase + l;
            const int idx = sidx[cell];
            const float* wrow = Wp + (size_t)idx * NCLS;
            float p[NCLS];
            float mx = -1e30f;
            #pragma unroll
            for (int c = 0; c < NCLS; c++) { p[c] = wrow[c]; mx = fmaxf(mx, p[c]); }
            float sum = 0.f;
            #pragma unroll
            for (int c = 0; c < NCLS; c++) { p[c] = __expf(p[c] - mx); sum += p[c]; }
            const float inv = 1.0f / sum;
            const float s = Sp[idx];
            float* orow = out + 2 + (size_t)cell * NCLS;
            float* prow = PP + (size_t)cell * 20;
            float* lrow = LL + (size_t)cell * 20;
            #pragma unroll
            for (int c = 0; c < NCLS; c++) {
                p[c] *= inv;
                const float lg = __logf(p[c] + 1e-8f);
                orow[c] = p[c];
                prow[c] = p[c];
                lrow[c] = lg;
                const float T1 = ct[0][l][c] + ct[1][l][c] + ct[2][l][c] + ct[3][l][c];
                const float T2 = ct[0][l][NCLS + c] + ct[1][l][NCLS + c]
                               + ct[2][l][NCLS + c] + ct[3][l][NCLS + c];
                ll += p[c] * (-0.5f * T1 + s * T2 - 0.5f * s * s * D[c]);
            }
            prow[17] = 0.f; prow[18] = 0.f; prow[19] = 0.f;
            lrow[17] = 0.f; lrow[18] = 0.f; lrow[19] = 0.f;
            #pragma unroll
            for (int h = 0; h < HIDN; h++) {
                XL[cell * HIDN + h] = ct[0][l][34 + h] + ct[1][l][34 + h]
                                    + ct[2][l][34 + h] + ct[3][l][34 + h] + blv[h];
                XR[cell * HIDN + h] = ct[0][l][42 + h] + ct[1][l][42 + h]
                                    + ct[2][l][42 + h] + ct[3][l][42 + h] + brv[h];
            }
        }
        #pragma unroll
        for (int o = 32; o; o >>= 1) ll += __shfl_xor(ll, o);
        if (l == 0) atomicAdd(out, ll * (1.0f / NSUB));
    }
}

// ---- fused edge + (last block) node reduce — NO fences (see round-8 analysis) ----
// NUM/DEN are only ever written by device-scope atomicAdd (coherent at LLC).
// __syncthreads() drains vmcnt(0) before the done-increment, so done==N-1 implies
// all adds complete. Last block reads via cache-bypassing atomic loads.
__global__ void k_edge(const int* __restrict__ ei, const float* __restrict__ XL,
                       const float* __restrict__ XR, const float* __restrict__ att,
                       const float* __restrict__ PP, const float* __restrict__ LL,
                       float* __restrict__ NUM, float* __restrict__ DEN,
                       unsigned* __restrict__ done, float* __restrict__ out) {
    const int tid = threadIdx.x;
    const int k = blockIdx.x * 256 + tid;
    if (k < NE) {
        const int s = ei[k], d = ei[NE + k];
        const float4 xa0 = *reinterpret_cast<const float4*>(XL + s * HIDN);
        const float4 xa1 = *reinterpret_cast<const float4*>(XL + s * HIDN + 4);
        const float4 xb0 = *reinterpret_cast<const float4*>(XR + d * HIDN);
        const float4 xb1 = *reinterpret_cast<const float4*>(XR + d * HIDN + 4);
        const float hv[8] = { xa0.x + xb0.x, xa0.y + xb0.y, xa0.z + xb0.z, xa0.w + xb0.w,
                              xa1.x + xb1.x, xa1.y + xb1.y, xa1.z + xb1.z, xa1.w + xb1.w };
        float e = 0.f;
        #pragma unroll
        for (int h = 0; h < HIDN; h++) {
            const float v = hv[h];
            e += ((v > 0.f) ? v : NEG_SLOPE * v) * att[h];
        }
        const float ex = __expf(e);        // no max-shift: |e| <~ 8, exp in f32 range
        float wgt = 0.f;
        #pragma unroll
        for (int q = 0; q < 5; q++) {
            const float4 ps = *reinterpret_cast<const float4*>(PP + (size_t)s * 20 + q * 4);
            const float4 ld = *reinterpret_cast<const float4*>(LL + (size_t)d * 20 + q * 4);
            wgt += ps.x * ld.x + ps.y * ld.y + ps.z * ld.z + ps.w * ld.w;
        }
        atomicAdd(NUM + d, ex * wgt);
        atomicAdd(DEN + d, ex);
    }

    __shared__ bool lastb;
    __syncthreads();                       // vmcnt(0): this block's atomics complete
    if (tid == 0)
        lastb = (atomicAdd(done, 1u) == gridDim.x - 1);
    __syncthreads();
    if (lastb) {
        float v = 0.f;
        for (int n = tid; n < NSUB; n += 256) {
            const float dd = __hip_atomic_load(DEN + n, __ATOMIC_RELAXED,
                                               __HIP_MEMORY_SCOPE_AGENT);
            if (dd > 0.f) {
                const float nu = __hip_atomic_load(NUM + n, __ATOMIC_RELAXED,
                                                   __HIP_MEMORY_SCOPE_AGENT);
                v += nu / dd;
            }
        }
        #pragma unroll
        for (int o = 32; o; o >>= 1) v += __shfl_xor(v, o);
        if ((tid & 63) == 0) atomicAdd(out + 1, -v * (1.0f / NSUB));
    }
}

extern "C" void kernel_launch(void* const* d_in, const int* in_sizes, int n_in,
                              void* d_out, int out_size, void* d_ws, size_t ws_size,
                              hipStream_t stream) {
    const float* x    = (const float*)d_in[0];
    const float* Mu   = (const float*)d_in[1];
    const float* Var  = (const float*)d_in[2];
    const int*   ei   = (const int*)d_in[3];
    const int*   sidx = (const int*)d_in[4];
    const float* Wp   = (const float*)d_in[5];
    const float* Sp   = (const float*)d_in[6];
    const float* Wl   = (const float*)d_in[7];
    const float* bl   = (const float*)d_in[8];
    const float* Wr   = (const float*)d_in[9];
    const float* br   = (const float*)d_in[10];
    const float* att  = (const float*)d_in[11];
    float* out = (float*)d_out;
    float* ws  = (float*)d_ws;

    unsigned short* B1 = (unsigned short*)(ws + OFF_B1);
    unsigned short* B2 = (unsigned short*)(ws + OFF_B2);
    float* D    = ws + OFF_D;
    float* XL   = ws + OFF_XL;
    float* XR   = ws + OFF_XR;
    float* PP   = ws + OFF_PP;
    float* LL   = ws + OFF_LL;
    float* NUM  = ws + OFF_NUM;
    float* DEN  = ws + OFF_DEN;
    unsigned* done = (unsigned*)(ws + OFF_DONE);

    (void)in_sizes; (void)n_in; (void)out_size; (void)ws_size;

    k_prep<<<100, 256, 0, stream>>>(Mu, Var, Wl, Wr, B1, B2, D, NUM, out);
    k_cell<<<NSUB / 16, 256, 0, stream>>>(x, sidx, Wp, Sp, bl, br, B1, B2, D,
                                          out, XL, XR, PP, LL);
    k_edge<<<(NE + 255) / 256, 256, 0, stream>>>(ei, XL, XR, att, PP, LL, NUM, DEN,
                                                 done, out);
}

// Round 9
// 46.532 us; speedup vs baseline: 1.5106x; 1.4155x over previous
//
#include <hip/hip_runtime.h>

#define NSUB   10000
#define NCLS   17
#define NG     500
#define NE     80000
#define HIDN   8
#define NEG_SLOPE 0.2f

typedef __attribute__((ext_vector_type(8))) short short8;
typedef __attribute__((ext_vector_type(4))) float f32x4;

// ws layout (float units)
#define OFF_B1   0                        // 512x64 bf16 = 16384 float slots
#define OFF_B2   16384                    // 512x32 bf16 = 8192 float slots
#define OFF_D    (OFF_B2 + 8192)          // 32
#define OFF_SP   (OFF_D + 32)             // NSUB*32: {xl[8], P[17], 0 x7} per node
#define OFF_DP   (OFF_SP + NSUB*32)       // NSUB*32: {xr[8], logP[17], 0 x7} per node
#define OFF_NUM  (OFF_DP + NSUB*32)       // NSUB
#define OFF_DEN  (OFF_NUM + NSUB)         // NSUB

__device__ __forceinline__ unsigned short f2bf(float f) {
    unsigned u = __float_as_uint(f);
    u += 0x7FFFu + ((u >> 16) & 1u);      // round-to-nearest-even
    return (unsigned short)(u >> 16);
}

#define MFMA16 __builtin_amdgcn_mfma_f32_16x16x32_bf16

// ---- prep: B1/B2 bf16 fragments, D[c], zero out[0..1] + NUM/DEN ----
__global__ void k_prep(const float* __restrict__ Mu, const float* __restrict__ Var,
                       const float* __restrict__ Wl, const float* __restrict__ Wr,
                       unsigned short* __restrict__ B1, unsigned short* __restrict__ B2,
                       float* __restrict__ D, float* __restrict__ zeroBase,
                       float* __restrict__ out) {
    const int b = blockIdx.x;
    if (b < 4) {
        const int t = b * 256 + threadIdx.x;        // 1024 threads = 16 ksteps * 64 lanes
        const int ks = t >> 6, lane = t & 63;
        const int fgrp = lane >> 4, fj = lane & 15;
        unsigned short v1[4][8], v2[2][8];
        #pragma unroll
        for (int e = 0; e < 8; e++) {
            const int g = ks * 32 + fgrp * 8 + e;
            const bool gv = (g < NG);
            #pragma unroll
            for (int nt = 0; nt < 4; nt++) {
                const int col = nt * 16 + fj;
                float v = 0.f;
                if (gv) {
                    if (col >= 17 && col < 34)      v = Mu[(col - 17) * NG + g] / Var[(col - 17) * NG + g];
                    else if (col >= 34 && col < 42) v = Wl[g * HIDN + (col - 34)];
                    else if (col >= 42 && col < 50) v = Wr[g * HIDN + (col - 42)];
                }
                v1[nt][e] = f2bf(v);
            }
            #pragma unroll
            for (int nt = 0; nt < 2; nt++) {
                const int col = nt * 16 + fj;
                float v = 0.f;
                if (gv && col < NCLS) v = 1.0f / Var[col * NG + g];
                v2[nt][e] = f2bf(v);
            }
        }
        #pragma unroll
        for (int nt = 0; nt < 4; nt++)
            *reinterpret_cast<short8*>(B1 + (size_t)((ks * 4 + nt) * 64 + lane) * 8) =
                *reinterpret_cast<short8*>(v1[nt]);
        #pragma unroll
        for (int nt = 0; nt < 2; nt++)
            *reinterpret_cast<short8*>(B2 + (size_t)((ks * 2 + nt) * 64 + lane) * 8) =
                *reinterpret_cast<short8*>(v2[nt]);
    } else if (b < 21) {
        const int c = b - 4;
        float s = 0.f;
        for (int g = threadIdx.x; g < NG; g += 256) {
            const float m = Mu[c * NG + g];
            s += m * m / Var[c * NG + g];
        }
        __shared__ float red[4];
        #pragma unroll
        for (int o = 32; o; o >>= 1) s += __shfl_xor(s, o);
        const int w = threadIdx.x >> 6, l = threadIdx.x & 63;
        if (l == 0) red[w] = s;
        __syncthreads();
        if (threadIdx.x == 0) D[c] = red[0] + red[1] + red[2] + red[3];
    } else {
        const int i = (b - 21) * 256 + threadIdx.x;   // zero NUM/DEN (2*NSUB)
        if (i < 2 * NSUB) zeroBase[i] = 0.f;
        if (b == 21 && threadIdx.x < 2) out[threadIdx.x] = 0.f;
    }
}

// ---- per-cell: MFMA GEMM, 1 tile (16 cells) per block, K split across 4 waves ----
// (round-6 inner loop, measured-good; epilogue writes packed SP/DP)
__launch_bounds__(256)
__global__ void k_cell(const float* __restrict__ x, const int* __restrict__ sidx,
                       const float* __restrict__ Wp, const float* __restrict__ Sp,
                       const float* __restrict__ blv, const float* __restrict__ brv,
                       const unsigned short* __restrict__ B1,
                       const unsigned short* __restrict__ B2,
                       const float* __restrict__ D,
                       float* __restrict__ out, float* __restrict__ SP,
                       float* __restrict__ DP) {
    const int tid = threadIdx.x;
    const int w = tid >> 6, l = tid & 63;
    const int grp = l >> 4, j = l & 15;
    const int rowbase = blockIdx.x * 16;             // 625 tiles exactly

    f32x4 a0 = {0,0,0,0}, a1 = {0,0,0,0}, a2 = {0,0,0,0}, a3 = {0,0,0,0};
    const float* xr = x + (size_t)(rowbase + j) * NG;
    const short8* b1 = reinterpret_cast<const short8*>(B1);
    const short8* b2 = reinterpret_cast<const short8*>(B2);

#define KSTEP(ks, fa, fb)                                                \
    {                                                                    \
        const short8* p1 = b1 + (size_t)((ks) * 4) * 64 + l;             \
        const short8* p2 = b2 + (size_t)((ks) * 2) * 64 + l;             \
        a0 = MFMA16(fa, p1[0],   a0, 0, 0, 0);                           \
        a1 = MFMA16(fa, p1[64],  a1, 0, 0, 0);                           \
        a2 = MFMA16(fa, p1[128], a2, 0, 0, 0);                           \
        a3 = MFMA16(fa, p1[192], a3, 0, 0, 0);                           \
        a0 = MFMA16(fb, p2[0],   a0, 0, 0, 0);                           \
        a1 = MFMA16(fb, p2[64],  a1, 0, 0, 0);                           \
    }

    const int ks0 = w * 4;
    #pragma unroll
    for (int i = 0; i < 3; i++) {
        const int ks = ks0 + i;
        const int g0 = ks * 32 + grp * 8;
        const float4 v0 = *reinterpret_cast<const float4*>(xr + g0);
        const float4 v1 = *reinterpret_cast<const float4*>(xr + g0 + 4);
        const float xv[8] = { v0.x, v0.y, v0.z, v0.w, v1.x, v1.y, v1.z, v1.w };
        short8 fa, fb;
        #pragma unroll
        for (int e = 0; e < 8; e++) { fa[e] = (short)f2bf(xv[e]); fb[e] = (short)f2bf(xv[e] * xv[e]); }
        KSTEP(ks, fa, fb);
    }
    if (w < 3) {
        const int ks = ks0 + 3;
        const int g0 = ks * 32 + grp * 8;
        const float4 v0 = *reinterpret_cast<const float4*>(xr + g0);
        const float4 v1 = *reinterpret_cast<const float4*>(xr + g0 + 4);
        const float xv[8] = { v0.x, v0.y, v0.z, v0.w, v1.x, v1.y, v1.z, v1.w };
        short8 fa, fb;
        #pragma unroll
        for (int e = 0; e < 8; e++) { fa[e] = (short)f2bf(xv[e]); fb[e] = (short)f2bf(xv[e] * xv[e]); }
        KSTEP(ks, fa, fb);
    } else {                                         // ks = 15 tail: genes 480..499 valid
        const int g0 = 480 + grp * 8;
        float4 v0 = {0,0,0,0}, v1 = {0,0,0,0};
        if (g0 <= 496) v0 = *reinterpret_cast<const float4*>(xr + g0);
        if (g0 <= 488) v1 = *reinterpret_cast<const float4*>(xr + g0 + 4);
        const float xv[8] = { v0.x, v0.y, v0.z, v0.w, v1.x, v1.y, v1.z, v1.w };
        short8 fa, fb;
        #pragma unroll
        for (int e = 0; e < 8; e++) { fa[e] = (short)f2bf(xv[e]); fb[e] = (short)f2bf(xv[e] * xv[e]); }
        KSTEP(15, fa, fb);
    }
#undef KSTEP

    // C layout: row = grp*4 + r, col = nt*16 + j (m89-verified)
    __shared__ float ct[4][16][68];
    #pragma unroll
    for (int r = 0; r < 4; r++) {
        ct[w][grp * 4 + r][j]      = a0[r];
        ct[w][grp * 4 + r][16 + j] = a1[r];
        ct[w][grp * 4 + r][32 + j] = a2[r];
        ct[w][grp * 4 + r][48 + j] = a3[r];
    }
    __syncthreads();

    if (w == 0) {
        float ll = 0.f;
        if (l < 16) {
            const int cell = rowbase + l;
            const int idx = sidx[cell];
            const float* wrow = Wp + (size_t)idx * NCLS;
            float p[NCLS];
            float mx = -1e30f;
            #pragma unroll
            for (int c = 0; c < NCLS; c++) { p[c] = wrow[c]; mx = fmaxf(mx, p[c]); }
            float sum = 0.f;
            #pragma unroll
            for (int c = 0; c < NCLS; c++) { p[c] = __expf(p[c] - mx); sum += p[c]; }
            const float inv = 1.0f / sum;
            const float s = Sp[idx];
            float* orow = out + 2 + (size_t)cell * NCLS;
            float* sp   = SP + (size_t)cell * 32;
            float* dp   = DP + (size_t)cell * 32;
            float ll_c = 0.f;
            #pragma unroll
            for (int c = 0; c < NCLS; c++) {
                p[c] *= inv;
                const float lg = __logf(p[c] + 1e-8f);
                orow[c]    = p[c];
                sp[8 + c]  = p[c];
                dp[8 + c]  = lg;
                const float T1 = ct[0][l][c] + ct[1][l][c] + ct[2][l][c] + ct[3][l][c];
                const float T2 = ct[0][l][NCLS + c] + ct[1][l][NCLS + c]
                               + ct[2][l][NCLS + c] + ct[3][l][NCLS + c];
                ll_c += p[c] * (-0.5f * T1 + s * T2 - 0.5f * s * s * D[c]);
            }
            ll = ll_c;
            #pragma unroll
            for (int q = 25; q < 32; q++) { sp[q] = 0.f; dp[q] = 0.f; }
            #pragma unroll
            for (int h = 0; h < HIDN; h++) {
                sp[h] = ct[0][l][34 + h] + ct[1][l][34 + h]
                      + ct[2][l][34 + h] + ct[3][l][34 + h] + blv[h];
                dp[h] = ct[0][l][42 + h] + ct[1][l][42 + h]
                      + ct[2][l][42 + h] + ct[3][l][42 + h] + brv[h];
            }
        }
        #pragma unroll
        for (int o = 32; o; o >>= 1) ll += __shfl_xor(ll, o);
        if (l == 0) atomicAdd(out, ll * (1.0f / NSUB));
    }
}

// ---- fused edge pass: 2-line packed gathers per side, no max-shift ----
__global__ void k_edge(const int* __restrict__ ei, const float* __restrict__ att,
                       const float* __restrict__ SP, const float* __restrict__ DP,
                       float* __restrict__ NUM, float* __restrict__ DEN) {
    const int k = blockIdx.x * 256 + threadIdx.x;
    if (k >= NE) return;
    const int s = ei[k], d = ei[NE + k];
    const float4* sp = reinterpret_cast<const float4*>(SP + (size_t)s * 32);
    const float4* dp = reinterpret_cast<const float4*>(DP + (size_t)d * 32);
    const float4 xa0 = sp[0], xa1 = sp[1];
    const float4 xb0 = dp[0], xb1 = dp[1];
    const float hv[8] = { xa0.x + xb0.x, xa0.y + xb0.y, xa0.z + xb0.z, xa0.w + xb0.w,
                          xa1.x + xb1.x, xa1.y + xb1.y, xa1.z + xb1.z, xa1.w + xb1.w };
    float e = 0.f;
    #pragma unroll
    for (int h = 0; h < HIDN; h++) {
        const float v = hv[h];
        e += ((v > 0.f) ? v : NEG_SLOPE * v) * att[h];
    }
    const float ex = __expf(e);            // no max-shift: |e| <~ 8, exp in f32 range
    float wgt = 0.f;
    #pragma unroll
    for (int q = 2; q < 7; q++) {          // P[17] + pad-zeros dot logP[17] + pad-zeros
        const float4 ps = sp[q];
        const float4 ld = dp[q];
        wgt += ps.x * ld.x + ps.y * ld.y + ps.z * ld.z + ps.w * ld.w;
    }
    atomicAdd(NUM + d, ex * wgt);
    atomicAdd(DEN + d, ex);
}

// ---- node pass: ce_space = -sum(num/den)/n ----
__global__ void k_node(const float* __restrict__ NUM, const float* __restrict__ DEN,
                       float* __restrict__ out) {
    const int n = blockIdx.x * 256 + threadIdx.x;
    float v = 0.f;
    if (n < NSUB) {
        const float dd = DEN[n];
        if (dd > 0.f) v = NUM[n] / dd;
    }
    #pragma unroll
    for (int o = 32; o; o >>= 1) v += __shfl_xor(v, o);
    if ((threadIdx.x & 63) == 0 && v != 0.f) atomicAdd(out + 1, -v * (1.0f / NSUB));
}

extern "C" void kernel_launch(void* const* d_in, const int* in_sizes, int n_in,
                              void* d_out, int out_size, void* d_ws, size_t ws_size,
                              hipStream_t stream) {
    const float* x    = (const float*)d_in[0];
    const float* Mu   = (const float*)d_in[1];
    const float* Var  = (const float*)d_in[2];
    const int*   ei   = (const int*)d_in[3];
    const int*   sidx = (const int*)d_in[4];
    const float* Wp   = (const float*)d_in[5];
    const float* Sp   = (const float*)d_in[6];
    const float* Wl   = (const float*)d_in[7];
    const float* bl   = (const float*)d_in[8];
    const float* Wr   = (const float*)d_in[9];
    const float* br   = (const float*)d_in[10];
    const float* att  = (const float*)d_in[11];
    float* out = (float*)d_out;
    float* ws  = (float*)d_ws;

    unsigned short* B1 = (unsigned short*)(ws + OFF_B1);
    unsigned short* B2 = (unsigned short*)(ws + OFF_B2);
    float* D    = ws + OFF_D;
    float* SP   = ws + OFF_SP;
    float* DP   = ws + OFF_DP;
    float* NUM  = ws + OFF_NUM;
    float* DEN  = ws + OFF_DEN;

    (void)in_sizes; (void)n_in; (void)out_size; (void)ws_size;

    k_prep<<<100, 256, 0, stream>>>(Mu, Var, Wl, Wr, B1, B2, D, NUM, out);
    k_cell<<<NSUB / 16, 256, 0, stream>>>(x, sidx, Wp, Sp, bl, br, B1, B2, D,
                                          out, SP, DP);
    k_edge<<<(NE + 255) / 256, 256, 0, stream>>>(ei, att, SP, DP, NUM, DEN);
    k_node<<<(NSUB + 255) / 256, 256, 0, stream>>>(NUM, DEN, out);
}